// Round 1
// 425.085 us; speedup vs baseline: 1.0720x; 1.0720x over previous
//
#include <hip/hip_runtime.h>
#include <math.h>

typedef unsigned short u16;
typedef _Float16 f16;
typedef __attribute__((ext_vector_type(8))) _Float16 f16x8;
typedef __attribute__((ext_vector_type(4))) float f32x4;

#define N_ROWS 131072
#define HID 128
#define WS_CH 8192                    // u16 per packed (layer,chunk) region: [hi|lo][nt][lane][c]
#define N_WCH 72                      // 2 layers * 36 chunks
#define N_PCH 8                       // 2 halves * 4 k-chunks of protos

// ---------------------------------------------------------------------------
// f16 split-2: v ≈ hi + lo with |v - hi - lo| <= 2^-22 |v|  (fp32-grade)
__device__ __forceinline__ void f16_split(float v, f16& hi, f16& lo) {
    f16 h = (f16)v;
    hi = h;
    lo = (f16)(v - (float)h);
}

// cardinal cubic B-spline on uniform knots g[j] = (j-3)*0.4 - 1 -> 8 coef slots
__device__ __forceinline__ void spline8(float xv, float* a8) {
    float s  = (xv + 2.2f) * 2.5f;
    float tf = floorf(s);
    int   tt = (int)tf;
    bool valid = (tt >= 0) && (tt <= 10);
    float kt = (float)(tt - 3) * 0.4f - 1.0f;
    float u  = (xv - kt) * 2.5f;
    float u2 = u * u, u3 = u2 * u;
    float om = 1.0f - u;
    float b3 = u3 * (1.0f / 6.0f);                                   // slot tt
    float b2 = (-3.f * u3 + 3.f * u2 + 3.f * u + 1.f) * (1.0f / 6.0f); // tt-1
    float b1 = (3.f * u3 - 6.f * u2 + 4.f) * (1.0f / 6.0f);          // tt-2
    float b0 = om * om * om * (1.0f / 6.0f);                         // tt-3
    #pragma unroll
    for (int c = 0; c < 8; ++c) {
        int d = tt - c;
        float v = 0.f;
        v = (d == 0) ? b3 : v;
        v = (d == 1) ? b2 : v;
        v = (d == 2) ? b1 : v;
        v = (d == 3) ? b0 : v;
        a8[c] = valid ? v : 0.f;
    }
}

// ---------------------------------------------------------------------------
// Pre-pack: weights (spline_w*scaler folded) and protos -> f16 hi/lo in MFMA
// B-fragment order. ws region r (u16 stride WS_CH):
//   r = l*36 + ch           : layer weights, B[k_local][o]
//   r = 72 + half*4 + kc    : protos,       B[k_local][p_local]
// in-region: idx = (nt*64 + kq*16 + n)*8 + c ; hi at +0, lo at +4096.
// Regions 0..79 are consumed strictly sequentially by kan_fused.
// ---------------------------------------------------------------------------
__global__ __launch_bounds__(256)
void pack_weights(const float* __restrict__ bw1, const float* __restrict__ sw1,
                  const float* __restrict__ sc1,
                  const float* __restrict__ bw2, const float* __restrict__ sw2,
                  const float* __restrict__ sc2,
                  const float* __restrict__ protos, u16* __restrict__ ws)
{
    int gid = blockIdx.x * 256 + threadIdx.x;
    if (gid < N_WCH * 4096) {
        int l  = gid / (36 * 4096);
        int r  = gid % (36 * 4096);
        int ch = r / 4096;
        int e  = r % 4096;             // o*32 + k_local
        int o  = e >> 5;
        int kl = e & 31;
        const float* bw = l ? bw2 : bw1;
        const float* sw = l ? sw2 : sw1;
        const float* sc = l ? sc2 : sc1;
        float v;
        if (ch < 4) {
            v = bw[o * HID + ch * 32 + kl];
        } else {
            int i = (ch - 4) * 4 + (kl >> 3);
            v = sw[(o * HID + i) * 8 + (kl & 7)] * sc[o * HID + i];
        }
        f16 hi, lo; f16_split(v, hi, lo);
        int nt = o >> 4, n = o & 15, kq = kl >> 3, c = kl & 7;
        size_t base = (size_t)(l * 36 + ch) * WS_CH;
        size_t idx  = ((size_t)nt * 64 + kq * 16 + n) * 8 + c;
        ws[base + idx]        = __builtin_bit_cast(u16, hi);
        ws[base + 4096 + idx] = __builtin_bit_cast(u16, lo);
    } else if (gid < (N_WCH + N_PCH) * 4096) {
        int r  = gid - N_WCH * 4096;
        int hk = r / 4096;             // half*4 + kc
        int e  = r % 4096;             // p_local*32 + kl
        int pl = e >> 5;
        int kl = e & 31;
        int half = hk >> 2, kc = hk & 3;
        float v = protos[(size_t)(half * 128 + pl) * HID + kc * 32 + kl];
        f16 hi, lo; f16_split(v, hi, lo);
        int nt = pl >> 4, n = pl & 15, kq = kl >> 3, c = kl & 7;
        size_t base = (size_t)(N_WCH + hk) * WS_CH;
        size_t idx  = ((size_t)nt * 64 + kq * 16 + n) * 8 + c;
        ws[base + idx]        = __builtin_bit_cast(u16, hi);
        ws[base + 4096 + idx] = __builtin_bit_cast(u16, lo);
    }
}

// ---------------------------------------------------------------------------
// Fused main kernel: x -> KAN layer1 -> KAN layer2 -> emb -> cosine argmax.
// Per block: 64 rows. Per wave: 16 rows; 16x16x32 f16 MFMA.
// Split scheme: 3 products (ah*bh + al*bh + ah*bl); the dropped al*bl term is
// <= 2^-22 relative — below fp32 accumulation noise.
//
// Pipeline (T14 async-STAGE, raw barriers — no vmcnt drain at barriers):
//   per chunk: A-prep(VALU) | B1(lgkm0+s_barrier) | ds_write staged regs |
//              issue global loads for chunk+1 | B2(lgkm0+s_barrier) | 24 MFMA
// Loads are issued one full chunk ahead and stay in flight across both
// barriers, hiding L2 latency under MFMA + next A-prep.
// t-tile rows are wave-private between the initial stage and the emb
// epilogue (C-write rows w*16+q*4+r == A-read rows w*16+m), so no extra
// barriers are needed at layer boundaries.
// ---------------------------------------------------------------------------
__global__ __launch_bounds__(256, 3)
void kan_fused(const float* __restrict__ x, const float* __restrict__ protos,
               const u16* __restrict__ wpack,
               float* __restrict__ emb_out, float* __restrict__ assign_out)
{
    __shared__ float t[64][132];          // x -> h -> emb tile
    __shared__ u16   Bfrag[2][8][64][8];  // [hi/lo][nt][lane(kq*16+n)][c]
    __shared__ float rnp[256];

    const int tid  = threadIdx.x;
    const int lane = tid & 63;
    const int w    = tid >> 6;            // wave 0..3
    const int m    = lane & 15;           // A-row / B-col within 16-tile
    const int q    = lane >> 4;           // 0..3
    const int row  = w * 16 + m;          // row within 64-row block tile
    const int brow = blockIdx.x * 64;
    const int woff = w * 256 + lane;      // uint4 index into a 16 KB region

    uint4 rr0, rr1, rr2, rr3;             // staged B regs (one chunk in flight)

#define ISSUE_LOADS(region) do {                                                   \
        const uint4* _g = (const uint4*)(wpack + (size_t)(region) * WS_CH) + woff; \
        rr0 = _g[0]; rr1 = _g[64]; rr2 = _g[128]; rr3 = _g[192];                   \
    } while (0)

#define STORE_LDS() do {                                                           \
        uint4* _l = (uint4*)&Bfrag[0][0][0][0] + woff;                             \
        _l[0] = rr0; _l[64] = rr1; _l[128] = rr2; _l[192] = rr3;                   \
    } while (0)

    // raw barrier: drain own LDS ops, sync execution, pin scheduling.
    // NO vmcnt drain -> prefetched global loads survive across it.
#define PIPE_BARRIER() do {                                                        \
        asm volatile("s_waitcnt lgkmcnt(0)" ::: "memory");                         \
        __builtin_amdgcn_s_barrier();                                              \
        __builtin_amdgcn_sched_barrier(0);                                         \
    } while (0)

    // prefetch chunk 0 as early as possible
    ISSUE_LOADS(0);

    // ---- proto inverse norms (one proto per thread) ----
    {
        const float4* pr = (const float4*)(protos + (size_t)tid * HID);
        float s = 0.0f;
        #pragma unroll
        for (int j = 0; j < 32; ++j) {
            float4 v = pr[j];
            s += v.x * v.x + v.y * v.y + v.z * v.z + v.w * v.w;
        }
        rnp[tid] = 1.0f / fmaxf(sqrtf(s), 1e-8f);
    }

    // ---- stage x tile ----
    {
        const int m2 = tid >> 2, kq2 = tid & 3;
        const float4* src = (const float4*)(x + (size_t)(brow + m2) * HID + kq2 * 32);
        #pragma unroll
        for (int j = 0; j < 8; ++j) {
            float4 v = src[j];
            int k = kq2 * 32 + j * 4;
            t[m2][k] = v.x; t[m2][k + 1] = v.y; t[m2][k + 2] = v.z; t[m2][k + 3] = v.w;
        }
    }
    PIPE_BARRIER();   // t + rnp visible to all waves; chunk-0 loads still in flight

    union { f16x8 v; f16 h[8]; } ah, al, bh, bl;
    f32x4 acc[8];

    // ================= two KAN layers =================
    for (int l = 0; l < 2; ++l) {
        #pragma unroll
        for (int nt = 0; nt < 8; ++nt) acc[nt] = (f32x4){0.f, 0.f, 0.f, 0.f};

        for (int ch = 0; ch < 36; ++ch) {
            // ---- A fragment in registers (VALU; overlaps other waves' MFMA) ----
            float a8[8];
            if (ch < 4) {
                const float4* tr = (const float4*)&t[row][ch * 32 + q * 8];
                float4 v0 = tr[0], v1 = tr[1];
                float xs[8] = {v0.x, v0.y, v0.z, v0.w, v1.x, v1.y, v1.z, v1.w};
                #pragma unroll
                for (int j = 0; j < 8; ++j)    // silu via v_exp + v_rcp (~2^-22 rel)
                    a8[j] = xs[j] * __builtin_amdgcn_rcpf(1.0f + __expf(-xs[j]));
            } else {
                spline8(t[row][(ch - 4) * 4 + q], a8);   // feature i0+q, 8 coefs
            }
            #pragma unroll
            for (int j = 0; j < 8; ++j) f16_split(a8[j], ah.h[j], al.h[j]);

            PIPE_BARRIER();                // B1: all waves done reading Bfrag(ch-1)
            STORE_LDS();                   // vmcnt wait on rr auto-inserted (loads ~1 chunk old)
            ISSUE_LOADS(l * 36 + ch + 1);  // prefetch next region (71 -> 72 = protos)
            PIPE_BARRIER();                // B2: all waves' ds_writes visible

            // ---- MFMAs: 8 col-tiles x 3 split products ----
            #pragma unroll
            for (int nt = 0; nt < 8; ++nt) {
                bh.v = *(const f16x8*)Bfrag[0][nt][lane];
                bl.v = *(const f16x8*)Bfrag[1][nt][lane];
                acc[nt] = __builtin_amdgcn_mfma_f32_16x16x32_f16(ah.v, bh.v, acc[nt], 0, 0, 0);
                acc[nt] = __builtin_amdgcn_mfma_f32_16x16x32_f16(al.v, bh.v, acc[nt], 0, 0, 0);
                acc[nt] = __builtin_amdgcn_mfma_f32_16x16x32_f16(ah.v, bl.v, acc[nt], 0, 0, 0);
            }
        }

        // ---- C/D -> t (col = lane&15, row = q*4 + reg) ----
        // rows w*16.. are wave-private: written and re-read only by wave w
        #pragma unroll
        for (int nt = 0; nt < 8; ++nt)
            #pragma unroll
            for (int r = 0; r < 4; ++r)
                t[w * 16 + q * 4 + r][nt * 16 + m] = acc[nt][r];
    }

    PIPE_BARRIER();   // cross-wave emb reads below need all C-writes visible

    // ---- emb epilogue: coalesced global write from t ----
    {
        const int m2 = tid >> 2, kq2 = tid & 3;
        float* dst = emb_out + (size_t)(brow + m2) * HID + kq2 * 32;
        #pragma unroll
        for (int j = 0; j < 8; ++j)
            *(float4*)(dst + j * 4) = *(const float4*)&t[m2][kq2 * 32 + j * 4];
    }

    // ================= cosine-sim argmax =================
    // row-norm is a positive per-row scale -> argmax-invariant; apply rnp only.
    float best[4]; int bi[4];
    #pragma unroll
    for (int r = 0; r < 4; ++r) { best[r] = -3.402823466e+38f; bi[r] = 0; }

    for (int half = 0; half < 2; ++half) {
        #pragma unroll
        for (int nt = 0; nt < 8; ++nt) acc[nt] = (f32x4){0.f, 0.f, 0.f, 0.f};

        for (int kc = 0; kc < 4; ++kc) {
            float a8[8];
            {
                const float4* tr = (const float4*)&t[row][kc * 32 + q * 8];
                float4 v0 = tr[0], v1 = tr[1];
                a8[0] = v0.x; a8[1] = v0.y; a8[2] = v0.z; a8[3] = v0.w;
                a8[4] = v1.x; a8[5] = v1.y; a8[6] = v1.z; a8[7] = v1.w;
            }
            #pragma unroll
            for (int j = 0; j < 8; ++j) f16_split(a8[j], ah.h[j], al.h[j]);

            PIPE_BARRIER();                // B1
            STORE_LDS();
            {
                int nxt = 72 + half * 4 + kc + 1;
                ISSUE_LOADS(nxt > 79 ? 79 : nxt);   // last iter: harmless re-load
            }
            PIPE_BARRIER();                // B2

            #pragma unroll
            for (int nt = 0; nt < 8; ++nt) {
                bh.v = *(const f16x8*)Bfrag[0][nt][lane];
                bl.v = *(const f16x8*)Bfrag[1][nt][lane];
                acc[nt] = __builtin_amdgcn_mfma_f32_16x16x32_f16(ah.v, bh.v, acc[nt], 0, 0, 0);
                acc[nt] = __builtin_amdgcn_mfma_f32_16x16x32_f16(al.v, bh.v, acc[nt], 0, 0, 0);
                acc[nt] = __builtin_amdgcn_mfma_f32_16x16x32_f16(ah.v, bl.v, acc[nt], 0, 0, 0);
            }
        }

        // ascending p within lane + strict '>' keeps FIRST max (np.argmax)
        #pragma unroll
        for (int nt = 0; nt < 8; ++nt) {
            int p = half * 128 + nt * 16 + m;
            float rp = rnp[p];
            #pragma unroll
            for (int r = 0; r < 4; ++r) {
                float v = acc[nt][r] * rp;
                if (v > best[r]) { best[r] = v; bi[r] = p; }
            }
        }
    }

    // reduce over the 16 lanes (cols) sharing each row; tie -> smaller index
    #pragma unroll
    for (int r = 0; r < 4; ++r) {
        #pragma unroll
        for (int off = 1; off < 16; off <<= 1) {
            float ov = __shfl_xor(best[r], off);
            int   oi = __shfl_xor(bi[r], off);
            if (ov > best[r] || (ov == best[r] && oi < bi[r])) { best[r] = ov; bi[r] = oi; }
        }
        if (m == 0)
            assign_out[(size_t)brow + w * 16 + q * 4 + r] = (float)bi[r];
    }
}

// ---------------------------------------------------------------------------
extern "C" void kernel_launch(void* const* d_in, const int* in_sizes, int n_in,
                              void* d_out, int out_size, void* d_ws, size_t ws_size,
                              hipStream_t stream) {
    (void)in_sizes; (void)n_in; (void)out_size; (void)ws_size;

    const float* x      = (const float*)d_in[0];
    const float* protos = (const float*)d_in[1];
    // d_in[2] = grid: uniform knots (j-3)*0.4 - 1, hardcoded
    const float* bw1 = (const float*)d_in[3];
    const float* sw1 = (const float*)d_in[4];
    const float* sc1 = (const float*)d_in[5];
    const float* bw2 = (const float*)d_in[6];
    const float* sw2 = (const float*)d_in[7];
    const float* sc2 = (const float*)d_in[8];

    float* out    = (float*)d_out;
    float* embp   = out;                             // (N,128)
    float* assign = out + (size_t)N_ROWS * HID;      // (N,) as float
    u16*   wpack  = (u16*)d_ws;                      // 1.31 MB packed fragments

    pack_weights<<<dim3((N_WCH + N_PCH) * 4096 / 256), dim3(256), 0, stream>>>(
        bw1, sw1, sc1, bw2, sw2, sc2, protos, wpack);
    kan_fused<<<dim3(N_ROWS / 64), dim3(256), 0, stream>>>(
        x, protos, wpack, embp, assign);
}